// Round 12
// baseline (212.688 us; speedup 1.0000x reference)
//
#include <hip/hip_runtime.h>

// USMSharp R18: R17 (batched hblur16 confirmed: ~42->~32us each) with blend's
// launch_bounds tightened (128,2)->(128,4).
// R17 finding: blend regressed <=41 -> 61us with BYTE-IDENTICAL source when
// hblur16's v[20] arrays entered the module (co-compilation RA perturbation,
// VGPR 64->96, occ 16%). (128,4) caps VGPR at 128 (>=96 needed, no spill)
// and forces the allocator toward a 4-waves/EU schedule.
// vblur_r: R11 body (known good ~20-25us steady).
// Attribute change only -> bit-identical output.
// K1 hblur16(img f32)->A bf16 ; K2 vblur_r(A) -> r=img-blur bf16
// K3 hblur16(mask(|r|*255>10))->Bh bf16 (aliases A) ; K4 vblur_blend+blend->out.

#define W 1920
#define H 1080
#define NP 6
#define PLANE (H * W)
#define TOT (NP * PLANE)
#define R 25
#define KS 51
#define TV 5                          // rows per thread
#define TBR 20                        // rows per block = 4 ty-groups * TV
#define NXT 15
#define NYT 54                        // 1080 / 20
#define WU_TOTAL (NXT * NYT * NP)     // 4860
#define WU_PER_XCD ((WU_TOTAL + 7) / 8)  // 608
#define NROWS (H * NP)                // 6480
#define NI (NROWS * 116)              // interior threads (chunks 2..117)
#define NBI ((NI + 127) / 128)        // 5873  (128-thread blocks)
#define NB (NROWS * 4)                // boundary threads (chunks 0,1,118,119)
#define NBB ((NB + 127) / 128)        // 203

__device__ __forceinline__ int reflect_idx(int i, int n) {
    if (i < 0) i = -i;
    if (i >= n) i = 2 * n - 2 - i;
    return i;
}
__device__ __forceinline__ float bf2f(unsigned short u) {
    return __uint_as_float(((unsigned int)u) << 16);
}
__device__ __forceinline__ unsigned short f2bf(float f) {  // RNE
    unsigned int x = __float_as_uint(f);
    return (unsigned short)((x + 0x7FFFu + ((x >> 16) & 1u)) >> 16);
}
__device__ __forceinline__ float maskf(float f) {
    return (fabsf(f) * 255.f > 10.f) ? 1.f : 0.f;
}

__global__ void compute_k1(const float* __restrict__ k2d, float* __restrict__ k1) {
    int t = threadIdx.x;
    if (t < KS) {
        float s = 0.f;
        for (int j = 0; j < KS; ++j) s += k2d[t * KS + j];
        k1[t] = s;
    }
}

// acc[o] = sum_k k1[k] * w[o+k+7], window w[i] = x[c0-32+i], i in [0,80)
// element p contributes to acc[o], o in [max(0,p-57), min(15,p-7)]
#define CONTRIB(P, VV)                                                   \
    {                                                                    \
        const int _p = (P);                                              \
        if (_p >= 7 && _p <= 72) {                                       \
            const int _olo = (_p - 57 > 0) ? _p - 57 : 0;                \
            const int _ohi = (_p - 7 < 15) ? _p - 7 : 15;                \
            _Pragma("unroll") for (int o = _olo; o <= _ohi; ++o)         \
                acc[o] += k1g[_p - 7 - o] * (VV);                        \
        }                                                                \
    }

template <bool MASK>
__global__ void __launch_bounds__(128, 2)
hblur16(const void* __restrict__ inv, unsigned short* __restrict__ out,
        const float* __restrict__ k1g) {
    const int b = blockIdx.x;
    float acc[16];
#pragma unroll
    for (int o = 0; o < 16; ++o) acc[o] = 0.f;
    int row, c0;
    if (b < NBI) {  // ---- interior: chunks 2..117, batched vector loads ----
        const int t = b * 128 + threadIdx.x;
        if (t >= NI) return;
        row = t / 116;
        c0 = (2 + (t - row * 116)) * 16;
        if constexpr (!MASK) {
            const float* rin = (const float*)inv + (size_t)row * W;
            // batch ALL 20 loads into explicit live ranges (two-piece recipe:
            // forced live ranges + launch_bounds cap; confirmed R17).
            float4 v[20];
#pragma unroll
            for (int i = 0; i < 20; ++i) v[i] = *(const float4*)(rin + c0 - 32 + 4 * i);
#pragma unroll
            for (int i = 0; i < 20; ++i) {
                CONTRIB(4 * i + 0, v[i].x);
                CONTRIB(4 * i + 1, v[i].y);
                CONTRIB(4 * i + 2, v[i].z);
                CONTRIB(4 * i + 3, v[i].w);
            }
        } else {
            const unsigned short* rin = (const unsigned short*)inv + (size_t)row * W;
            uint4 u[10];
#pragma unroll
            for (int i = 0; i < 10; ++i) u[i] = *(const uint4*)(rin + c0 - 32 + 8 * i);
#pragma unroll
            for (int i = 0; i < 10; ++i) {
#pragma unroll
                for (int h = 0; h < 4; ++h) {
                    const unsigned int c = (h == 0) ? u[i].x : (h == 1) ? u[i].y : (h == 2) ? u[i].z : u[i].w;
                    const float flo = __uint_as_float(c << 16);
                    const float fhi = __uint_as_float(c & 0xffff0000u);
                    CONTRIB(8 * i + 2 * h + 0, maskf(flo));
                    CONTRIB(8 * i + 2 * h + 1, maskf(fhi));
                }
            }
        }
    } else {  // ---- boundary: chunks 0,1,118,119, scalar reflect loads ----
        const int t = (b - NBI) * 128 + threadIdx.x;
        if (t >= NB) return;
        row = t >> 2;
        const int q = t & 3;
        c0 = ((q < 2) ? q : q + 116) * 16;
        if constexpr (!MASK) {
            const float* rin = (const float*)inv + (size_t)row * W;
#pragma unroll
            for (int i = 7; i <= 72; ++i) {
                float vv = rin[reflect_idx(c0 - 32 + i, W)];
                CONTRIB(i, vv);
            }
        } else {
            const unsigned short* rin = (const unsigned short*)inv + (size_t)row * W;
#pragma unroll
            for (int i = 7; i <= 72; ++i) {
                float vv = maskf(bf2f(rin[reflect_idx(c0 - 32 + i, W)]));
                CONTRIB(i, vv);
            }
        }
    }
    // pack 16 bf16 -> 2 x 16B stores
    uint4 o0, o1;
    o0.x = (unsigned int)f2bf(acc[0]) | ((unsigned int)f2bf(acc[1]) << 16);
    o0.y = (unsigned int)f2bf(acc[2]) | ((unsigned int)f2bf(acc[3]) << 16);
    o0.z = (unsigned int)f2bf(acc[4]) | ((unsigned int)f2bf(acc[5]) << 16);
    o0.w = (unsigned int)f2bf(acc[6]) | ((unsigned int)f2bf(acc[7]) << 16);
    o1.x = (unsigned int)f2bf(acc[8]) | ((unsigned int)f2bf(acc[9]) << 16);
    o1.y = (unsigned int)f2bf(acc[10]) | ((unsigned int)f2bf(acc[11]) << 16);
    o1.z = (unsigned int)f2bf(acc[12]) | ((unsigned int)f2bf(acc[13]) << 16);
    o1.w = (unsigned int)f2bf(acc[14]) | ((unsigned int)f2bf(acc[15]) << 16);
    unsigned short* op = out + (size_t)row * W + c0;
    *(uint4*)op = o0;
    *(uint4*)(op + 8) = o1;
}

// ---- vertical conv: register rolling, TV rows x 4 cols per thread ---------
__device__ __forceinline__ bool decode_wu(int lin, int& p, int& yt, int& xt) {
    int c = lin & 7, j = lin >> 3;
    int wu = c * WU_PER_XCD + j;
    if (wu >= WU_TOTAL) return false;
    p = wu / (NXT * NYT);
    int rem = wu - p * (NXT * NYT);
    yt = rem / NXT;
    xt = rem - yt * NXT;
    return true;
}

__device__ __forceinline__ void vconvT(const unsigned short* __restrict__ Ap, int x4, int y0,
                                       const float* __restrict__ k1g, float4 acc[TV]) {
#pragma unroll
    for (int j = 0; j < TV; ++j) acc[j] = make_float4(0.f, 0.f, 0.f, 0.f);
    if (y0 >= R && y0 + TV - 1 + R < H) {
        const unsigned short* p = Ap + (size_t)(y0 - R) * W + x4;
#pragma unroll
        for (int u = 0; u < TV + 2 * R; ++u) {
            ushort4 s = *(const ushort4*)p;
            p += W;
            float4 v = make_float4(bf2f(s.x), bf2f(s.y), bf2f(s.z), bf2f(s.w));
            const int jlo = (u - 2 * R > 0) ? u - 2 * R : 0;
            const int jhi = (u < TV - 1) ? u : TV - 1;
#pragma unroll
            for (int j = jlo; j <= jhi; ++j) {
                const float k = k1g[u - j];
                acc[j].x += k * v.x; acc[j].y += k * v.y;
                acc[j].z += k * v.z; acc[j].w += k * v.w;
            }
        }
    } else {
#pragma unroll
        for (int u = 0; u < TV + 2 * R; ++u) {
            int yy = reflect_idx(y0 - R + u, H);
            ushort4 s = *(const ushort4*)(Ap + (size_t)yy * W + x4);
            float4 v = make_float4(bf2f(s.x), bf2f(s.y), bf2f(s.z), bf2f(s.w));
            const int jlo = (u - 2 * R > 0) ? u - 2 * R : 0;
            const int jhi = (u < TV - 1) ? u : TV - 1;
#pragma unroll
            for (int j = jlo; j <= jhi; ++j) {
                const float k = k1g[u - j];
                acc[j].x += k * v.x; acc[j].y += k * v.y;
                acc[j].z += k * v.z; acc[j].w += k * v.w;
            }
        }
    }
}

__global__ void vblur_r(const unsigned short* __restrict__ A, const float* __restrict__ img,
                        const float* __restrict__ k1g, unsigned short* __restrict__ rbuf) {
    int p, yt, xt;
    if (!decode_wu(blockIdx.x, p, yt, xt)) return;
    const int tx = threadIdx.x & 31, ty = threadIdx.x >> 5;  // 128 thr: ty 0..3
    const int x4 = xt * 128 + tx * 4;
    const int y0 = yt * TBR + ty * TV;
    float4 acc[TV];
    vconvT(A + (size_t)p * PLANE, x4, y0, k1g, acc);
#pragma unroll
    for (int j = 0; j < TV; ++j) {
        size_t idx = (size_t)p * PLANE + (size_t)(y0 + j) * W + x4;
        float4 iv = *(const float4*)&img[idx];
        ushort4 rr;
        rr.x = f2bf(iv.x - acc[j].x);
        rr.y = f2bf(iv.y - acc[j].y);
        rr.z = f2bf(iv.z - acc[j].z);
        rr.w = f2bf(iv.w - acc[j].w);
        *(ushort4*)&rbuf[idx] = rr;
    }
}

__global__ void __launch_bounds__(128, 4)
vblur_blend(const unsigned short* __restrict__ Bh, const float* __restrict__ img,
            const unsigned short* __restrict__ rbuf,
            const float* __restrict__ k1g, float* __restrict__ out) {
    int p, yt, xt;
    if (!decode_wu(blockIdx.x, p, yt, xt)) return;
    const int tx = threadIdx.x & 31, ty = threadIdx.x >> 5;  // 128 thr: ty 0..3
    const int x4 = xt * 128 + tx * 4;
    const int y0 = yt * TBR + ty * TV;
    const size_t idx0 = (size_t)p * PLANE + (size_t)y0 * W + x4;
    // issue-early epilogue loads (img + rbuf), then conv, then compute+store.
    float4 iv[TV];
    ushort4 ru[TV];
#pragma unroll
    for (int j = 0; j < TV; ++j) {
        iv[j] = *(const float4*)&img[idx0 + (size_t)j * W];
        ru[j] = *(const ushort4*)&rbuf[idx0 + (size_t)j * W];
    }
    float4 acc[TV];
    vconvT(Bh + (size_t)p * PLANE, x4, y0, k1g, acc);
#pragma unroll
    for (int j = 0; j < TV; ++j) {
        float dx = fminf(fmaxf(iv[j].x + 0.5f * bf2f(ru[j].x), 0.f), 1.f) - iv[j].x;
        float dy = fminf(fmaxf(iv[j].y + 0.5f * bf2f(ru[j].y), 0.f), 1.f) - iv[j].y;
        float dz = fminf(fmaxf(iv[j].z + 0.5f * bf2f(ru[j].z), 0.f), 1.f) - iv[j].z;
        float dw = fminf(fmaxf(iv[j].w + 0.5f * bf2f(ru[j].w), 0.f), 1.f) - iv[j].w;
        float4 o;
        o.x = iv[j].x + acc[j].x * dx;
        o.y = iv[j].y + acc[j].y * dy;
        o.z = iv[j].z + acc[j].z * dz;
        o.w = iv[j].w + acc[j].w * dw;
        *(float4*)&out[idx0 + (size_t)j * W] = o;
    }
}

extern "C" void kernel_launch(void* const* d_in, const int* in_sizes, int n_in,
                              void* d_out, int out_size, void* d_ws, size_t ws_size,
                              hipStream_t stream) {
    const float* img = (const float*)d_in[0];
    const float* k2d = (const float*)d_in[1];
    float* out = (float*)d_out;

    unsigned short* AB = (unsigned short*)d_ws;  // A, later Bh
    unsigned short* rbuf = AB + TOT;             // residual bf16
    float* k1 = (float*)(rbuf + TOT);

    const int gridHB = NBI + NBB;        // 6076  (128-thread blocks)
    const int gridVB = 8 * WU_PER_XCD;   // 4864  (128-thread blocks)

    hipLaunchKernelGGL(compute_k1, dim3(1), dim3(64), 0, stream, k2d, k1);
    hipLaunchKernelGGL((hblur16<false>), dim3(gridHB), dim3(128), 0, stream, (const void*)img, AB, k1);
    hipLaunchKernelGGL(vblur_r, dim3(gridVB), dim3(128), 0, stream, AB, img, k1, rbuf);
    hipLaunchKernelGGL((hblur16<true>), dim3(gridHB), dim3(128), 0, stream, (const void*)rbuf, AB, k1);
    hipLaunchKernelGGL(vblur_blend, dim3(gridVB), dim3(128), 0, stream, AB, img, rbuf, k1, out);
}

// Round 13
// 193.498 us; speedup vs baseline: 1.0992x; 1.0992x over previous
//
#include <hip/hip_runtime.h>

// USMSharp R19: stabilize blend's bistable register allocation.
// Blend history (same body): <=41 (R15/R16 modules), 61 (R17: VGPR96/occ16%),
// 53.5+spill (R18: bounds(128,4) -> VGPR64 + 68MB scratch writes).
// Levers: (1) named scalars iv0..4/ru0..4 instead of arrays (kills the
// aggregate-spill pathway of R14/R18); (2) bounds(128,3) -> VGPR cap 170;
// (3) blend defined BEFORE hblur16 so its RA context is not downstream of
// hblur's v[20] arrays (rule-#19 co-compilation perturbation).
// hblur16: R17 batched form (confirmed ~42->~32us each). vblur_r: R11 form.
// Naming/attribute/order changes only -> bit-identical output.
// Decisive counter: blend WRITE_SIZE 48600 (clean) vs 116865 (spill).

#define W 1920
#define H 1080
#define NP 6
#define PLANE (H * W)
#define TOT (NP * PLANE)
#define R 25
#define KS 51
#define TV 5                          // rows per thread
#define TBR 20                        // rows per block = 4 ty-groups * TV
#define NXT 15
#define NYT 54                        // 1080 / 20
#define WU_TOTAL (NXT * NYT * NP)     // 4860
#define WU_PER_XCD ((WU_TOTAL + 7) / 8)  // 608
#define NROWS (H * NP)                // 6480
#define NI (NROWS * 116)              // interior threads (chunks 2..117)
#define NBI ((NI + 127) / 128)        // 5873  (128-thread blocks)
#define NB (NROWS * 4)                // boundary threads (chunks 0,1,118,119)
#define NBB ((NB + 127) / 128)        // 203

__device__ __forceinline__ int reflect_idx(int i, int n) {
    if (i < 0) i = -i;
    if (i >= n) i = 2 * n - 2 - i;
    return i;
}
__device__ __forceinline__ float bf2f(unsigned short u) {
    return __uint_as_float(((unsigned int)u) << 16);
}
__device__ __forceinline__ unsigned short f2bf(float f) {  // RNE
    unsigned int x = __float_as_uint(f);
    return (unsigned short)((x + 0x7FFFu + ((x >> 16) & 1u)) >> 16);
}
__device__ __forceinline__ float maskf(float f) {
    return (fabsf(f) * 255.f > 10.f) ? 1.f : 0.f;
}

__global__ void compute_k1(const float* __restrict__ k2d, float* __restrict__ k1) {
    int t = threadIdx.x;
    if (t < KS) {
        float s = 0.f;
        for (int j = 0; j < KS; ++j) s += k2d[t * KS + j];
        k1[t] = s;
    }
}

// ---- vertical conv: register rolling, TV rows x 4 cols per thread ---------
__device__ __forceinline__ bool decode_wu(int lin, int& p, int& yt, int& xt) {
    int c = lin & 7, j = lin >> 3;
    int wu = c * WU_PER_XCD + j;
    if (wu >= WU_TOTAL) return false;
    p = wu / (NXT * NYT);
    int rem = wu - p * (NXT * NYT);
    yt = rem / NXT;
    xt = rem - yt * NXT;
    return true;
}

__device__ __forceinline__ void vconvT(const unsigned short* __restrict__ Ap, int x4, int y0,
                                       const float* __restrict__ k1g, float4 acc[TV]) {
#pragma unroll
    for (int j = 0; j < TV; ++j) acc[j] = make_float4(0.f, 0.f, 0.f, 0.f);
    if (y0 >= R && y0 + TV - 1 + R < H) {
        const unsigned short* p = Ap + (size_t)(y0 - R) * W + x4;
#pragma unroll
        for (int u = 0; u < TV + 2 * R; ++u) {
            ushort4 s = *(const ushort4*)p;
            p += W;
            float4 v = make_float4(bf2f(s.x), bf2f(s.y), bf2f(s.z), bf2f(s.w));
            const int jlo = (u - 2 * R > 0) ? u - 2 * R : 0;
            const int jhi = (u < TV - 1) ? u : TV - 1;
#pragma unroll
            for (int j = jlo; j <= jhi; ++j) {
                const float k = k1g[u - j];
                acc[j].x += k * v.x; acc[j].y += k * v.y;
                acc[j].z += k * v.z; acc[j].w += k * v.w;
            }
        }
    } else {
#pragma unroll
        for (int u = 0; u < TV + 2 * R; ++u) {
            int yy = reflect_idx(y0 - R + u, H);
            ushort4 s = *(const ushort4*)(Ap + (size_t)yy * W + x4);
            float4 v = make_float4(bf2f(s.x), bf2f(s.y), bf2f(s.z), bf2f(s.w));
            const int jlo = (u - 2 * R > 0) ? u - 2 * R : 0;
            const int jhi = (u < TV - 1) ? u : TV - 1;
#pragma unroll
            for (int j = jlo; j <= jhi; ++j) {
                const float k = k1g[u - j];
                acc[j].x += k * v.x; acc[j].y += k * v.y;
                acc[j].z += k * v.z; acc[j].w += k * v.w;
            }
        }
    }
}

__global__ void vblur_r(const unsigned short* __restrict__ A, const float* __restrict__ img,
                        const float* __restrict__ k1g, unsigned short* __restrict__ rbuf) {
    int p, yt, xt;
    if (!decode_wu(blockIdx.x, p, yt, xt)) return;
    const int tx = threadIdx.x & 31, ty = threadIdx.x >> 5;  // 128 thr: ty 0..3
    const int x4 = xt * 128 + tx * 4;
    const int y0 = yt * TBR + ty * TV;
    float4 acc[TV];
    vconvT(A + (size_t)p * PLANE, x4, y0, k1g, acc);
#pragma unroll
    for (int j = 0; j < TV; ++j) {
        size_t idx = (size_t)p * PLANE + (size_t)(y0 + j) * W + x4;
        float4 iv = *(const float4*)&img[idx];
        ushort4 rr;
        rr.x = f2bf(iv.x - acc[j].x);
        rr.y = f2bf(iv.y - acc[j].y);
        rr.z = f2bf(iv.z - acc[j].z);
        rr.w = f2bf(iv.w - acc[j].w);
        *(ushort4*)&rbuf[idx] = rr;
    }
}

__global__ void __launch_bounds__(128, 3)
vblur_blend(const unsigned short* __restrict__ Bh, const float* __restrict__ img,
            const unsigned short* __restrict__ rbuf,
            const float* __restrict__ k1g, float* __restrict__ out) {
    int p, yt, xt;
    if (!decode_wu(blockIdx.x, p, yt, xt)) return;
    const int tx = threadIdx.x & 31, ty = threadIdx.x >> 5;  // 128 thr: ty 0..3
    const int x4 = xt * 128 + tx * 4;
    const int y0 = yt * TBR + ty * TV;
    const size_t idx0 = (size_t)p * PLANE + (size_t)y0 * W + x4;
    // issue-early epilogue loads as NAMED SCALARS (no aggregate to spill).
    float4 iv0 = *(const float4*)&img[idx0];
    float4 iv1 = *(const float4*)&img[idx0 + (size_t)W];
    float4 iv2 = *(const float4*)&img[idx0 + (size_t)2 * W];
    float4 iv3 = *(const float4*)&img[idx0 + (size_t)3 * W];
    float4 iv4 = *(const float4*)&img[idx0 + (size_t)4 * W];
    ushort4 ru0 = *(const ushort4*)&rbuf[idx0];
    ushort4 ru1 = *(const ushort4*)&rbuf[idx0 + (size_t)W];
    ushort4 ru2 = *(const ushort4*)&rbuf[idx0 + (size_t)2 * W];
    ushort4 ru3 = *(const ushort4*)&rbuf[idx0 + (size_t)3 * W];
    ushort4 ru4 = *(const ushort4*)&rbuf[idx0 + (size_t)4 * W];
    float4 acc[TV];
    vconvT(Bh + (size_t)p * PLANE, x4, y0, k1g, acc);
#define BLEND_ROW(J, IV, RU)                                                    \
    {                                                                           \
        float dx = fminf(fmaxf((IV).x + 0.5f * bf2f((RU).x), 0.f), 1.f) - (IV).x; \
        float dy = fminf(fmaxf((IV).y + 0.5f * bf2f((RU).y), 0.f), 1.f) - (IV).y; \
        float dz = fminf(fmaxf((IV).z + 0.5f * bf2f((RU).z), 0.f), 1.f) - (IV).z; \
        float dw = fminf(fmaxf((IV).w + 0.5f * bf2f((RU).w), 0.f), 1.f) - (IV).w; \
        float4 o;                                                               \
        o.x = (IV).x + acc[J].x * dx;                                           \
        o.y = (IV).y + acc[J].y * dy;                                           \
        o.z = (IV).z + acc[J].z * dz;                                           \
        o.w = (IV).w + acc[J].w * dw;                                           \
        *(float4*)&out[idx0 + (size_t)(J) * W] = o;                             \
    }
    BLEND_ROW(0, iv0, ru0);
    BLEND_ROW(1, iv1, ru1);
    BLEND_ROW(2, iv2, ru2);
    BLEND_ROW(3, iv3, ru3);
    BLEND_ROW(4, iv4, ru4);
#undef BLEND_ROW
}

// acc[o] = sum_k k1[k] * w[o+k+7], window w[i] = x[c0-32+i], i in [0,80)
// element p contributes to acc[o], o in [max(0,p-57), min(15,p-7)]
#define CONTRIB(P, VV)                                                   \
    {                                                                    \
        const int _p = (P);                                              \
        if (_p >= 7 && _p <= 72) {                                       \
            const int _olo = (_p - 57 > 0) ? _p - 57 : 0;                \
            const int _ohi = (_p - 7 < 15) ? _p - 7 : 15;                \
            _Pragma("unroll") for (int o = _olo; o <= _ohi; ++o)         \
                acc[o] += k1g[_p - 7 - o] * (VV);                        \
        }                                                                \
    }

template <bool MASK>
__global__ void __launch_bounds__(128, 2)
hblur16(const void* __restrict__ inv, unsigned short* __restrict__ out,
        const float* __restrict__ k1g) {
    const int b = blockIdx.x;
    float acc[16];
#pragma unroll
    for (int o = 0; o < 16; ++o) acc[o] = 0.f;
    int row, c0;
    if (b < NBI) {  // ---- interior: chunks 2..117, batched vector loads ----
        const int t = b * 128 + threadIdx.x;
        if (t >= NI) return;
        row = t / 116;
        c0 = (2 + (t - row * 116)) * 16;
        if constexpr (!MASK) {
            const float* rin = (const float*)inv + (size_t)row * W;
            float4 v[20];
#pragma unroll
            for (int i = 0; i < 20; ++i) v[i] = *(const float4*)(rin + c0 - 32 + 4 * i);
#pragma unroll
            for (int i = 0; i < 20; ++i) {
                CONTRIB(4 * i + 0, v[i].x);
                CONTRIB(4 * i + 1, v[i].y);
                CONTRIB(4 * i + 2, v[i].z);
                CONTRIB(4 * i + 3, v[i].w);
            }
        } else {
            const unsigned short* rin = (const unsigned short*)inv + (size_t)row * W;
            uint4 u[10];
#pragma unroll
            for (int i = 0; i < 10; ++i) u[i] = *(const uint4*)(rin + c0 - 32 + 8 * i);
#pragma unroll
            for (int i = 0; i < 10; ++i) {
#pragma unroll
                for (int h = 0; h < 4; ++h) {
                    const unsigned int c = (h == 0) ? u[i].x : (h == 1) ? u[i].y : (h == 2) ? u[i].z : u[i].w;
                    const float flo = __uint_as_float(c << 16);
                    const float fhi = __uint_as_float(c & 0xffff0000u);
                    CONTRIB(8 * i + 2 * h + 0, maskf(flo));
                    CONTRIB(8 * i + 2 * h + 1, maskf(fhi));
                }
            }
        }
    } else {  // ---- boundary: chunks 0,1,118,119, scalar reflect loads ----
        const int t = (b - NBI) * 128 + threadIdx.x;
        if (t >= NB) return;
        row = t >> 2;
        const int q = t & 3;
        c0 = ((q < 2) ? q : q + 116) * 16;
        if constexpr (!MASK) {
            const float* rin = (const float*)inv + (size_t)row * W;
#pragma unroll
            for (int i = 7; i <= 72; ++i) {
                float vv = rin[reflect_idx(c0 - 32 + i, W)];
                CONTRIB(i, vv);
            }
        } else {
            const unsigned short* rin = (const unsigned short*)inv + (size_t)row * W;
#pragma unroll
            for (int i = 7; i <= 72; ++i) {
                float vv = maskf(bf2f(rin[reflect_idx(c0 - 32 + i, W)]));
                CONTRIB(i, vv);
            }
        }
    }
    // pack 16 bf16 -> 2 x 16B stores
    uint4 o0, o1;
    o0.x = (unsigned int)f2bf(acc[0]) | ((unsigned int)f2bf(acc[1]) << 16);
    o0.y = (unsigned int)f2bf(acc[2]) | ((unsigned int)f2bf(acc[3]) << 16);
    o0.z = (unsigned int)f2bf(acc[4]) | ((unsigned int)f2bf(acc[5]) << 16);
    o0.w = (unsigned int)f2bf(acc[6]) | ((unsigned int)f2bf(acc[7]) << 16);
    o1.x = (unsigned int)f2bf(acc[8]) | ((unsigned int)f2bf(acc[9]) << 16);
    o1.y = (unsigned int)f2bf(acc[10]) | ((unsigned int)f2bf(acc[11]) << 16);
    o1.z = (unsigned int)f2bf(acc[12]) | ((unsigned int)f2bf(acc[13]) << 16);
    o1.w = (unsigned int)f2bf(acc[14]) | ((unsigned int)f2bf(acc[15]) << 16);
    unsigned short* op = out + (size_t)row * W + c0;
    *(uint4*)op = o0;
    *(uint4*)(op + 8) = o1;
}

extern "C" void kernel_launch(void* const* d_in, const int* in_sizes, int n_in,
                              void* d_out, int out_size, void* d_ws, size_t ws_size,
                              hipStream_t stream) {
    const float* img = (const float*)d_in[0];
    const float* k2d = (const float*)d_in[1];
    float* out = (float*)d_out;

    unsigned short* AB = (unsigned short*)d_ws;  // A, later Bh
    unsigned short* rbuf = AB + TOT;             // residual bf16
    float* k1 = (float*)(rbuf + TOT);

    const int gridHB = NBI + NBB;        // 6076  (128-thread blocks)
    const int gridVB = 8 * WU_PER_XCD;   // 4864  (128-thread blocks)

    hipLaunchKernelGGL(compute_k1, dim3(1), dim3(64), 0, stream, k2d, k1);
    hipLaunchKernelGGL((hblur16<false>), dim3(gridHB), dim3(128), 0, stream, (const void*)img, AB, k1);
    hipLaunchKernelGGL(vblur_r, dim3(gridVB), dim3(128), 0, stream, AB, img, k1, rbuf);
    hipLaunchKernelGGL((hblur16<true>), dim3(gridHB), dim3(128), 0, stream, (const void*)rbuf, AB, k1);
    hipLaunchKernelGGL(vblur_blend, dim3(gridVB), dim3(128), 0, stream, AB, img, rbuf, k1, out);
}